// Round 8
// baseline (285.955 us; speedup 1.0000x reference)
//
#include <hip/hip_runtime.h>

#define CCH 64     // channels
#define BPB 256    // fine bins per coarse bucket
#define NBMAX 1024 // max coarse buckets (M/BPB = 1024 here)
#define ELPB 4096  // elements per partition block

typedef _Float16 half4v __attribute__((ext_vector_type(4)));   // 8 B
typedef _Float16 half8v __attribute__((ext_vector_type(8)));   // 16 B

__device__ __forceinline__ float4 f4zero() { return make_float4(0.f, 0.f, 0.f, 0.f); }

// ---- P1: per-block histogram of coarse buckets (LDS atomics only).
// Fused: grid-stride fp32->fp16 conversion of inp into inp16 scratch. ----
__global__ void p1_hist(const int* __restrict__ os, int* __restrict__ cnt,
                        const float4* __restrict__ inp4, half4v* __restrict__ inp16,
                        int n4, int total, int nblk, int nb) {
    __shared__ int hist[NBMAX];
    int tid = threadIdx.x;
    for (int b = tid; b < nb; b += 256) hist[b] = 0;
    __syncthreads();
    int start = blockIdx.x * ELPB;
    for (int i = 0; i < ELPB / 256; ++i) {
        int idx = start + i * 256 + tid;
        if (idx < total) atomicAdd(&hist[os[idx] >> 8], 1);
    }
    // fp32 -> fp16 convert of inp (independent, coalesced, grid-stride)
    int gstride = gridDim.x * 256;
    for (int i = blockIdx.x * 256 + tid; i < n4; i += gstride) {
        float4 v = inp4[i];
        half4v h;
        h[0] = (_Float16)v.x; h[1] = (_Float16)v.y;
        h[2] = (_Float16)v.z; h[3] = (_Float16)v.w;
        inp16[i] = h;
    }
    __syncthreads();
    for (int b = tid; b < nb; b += 256)
        cnt[b * nblk + blockIdx.x] = hist[b];
}

// ---- P2a: per-bucket exclusive scan across blocks (one wave per bucket) ----
__global__ void p2a_scan(int* __restrict__ cnt, int* __restrict__ btot,
                         int nblk, int nb) {
    int wid  = (blockIdx.x * blockDim.x + threadIdx.x) >> 6;
    int lane = threadIdx.x & 63;
    if (wid >= nb) return;
    int running = 0;
    for (int c = 0; c < nblk; c += 64) {
        int in_r = (c + lane < nblk);
        int idx = wid * nblk + c + lane;
        int v = in_r ? cnt[idx] : 0;
        int s = v;
        for (int d = 1; d < 64; d <<= 1) { int t = __shfl_up(s, d); if (lane >= d) s += t; }
        if (in_r) cnt[idx] = running + s - v;
        running += __shfl(s, 63);
    }
    if (lane == 0) btot[wid] = running;
}

// ---- P2b: exclusive scan of bucket totals -> base[]; base[nb] = total ----
__global__ void p2b_base(const int* __restrict__ btot, int* __restrict__ base, int nb) {
    __shared__ int wtot[16];
    int tid = threadIdx.x, lane = tid & 63, w = tid >> 6;
    int v = (tid < nb) ? btot[tid] : 0;
    int s = v;
    for (int d = 1; d < 64; d <<= 1) { int t = __shfl_up(s, d); if (lane >= d) s += t; }
    if (lane == 63) wtot[w] = s;
    __syncthreads();
    if (w == 0) {
        int wv = (lane < 16) ? wtot[lane] : 0;
        int ss = wv;
        for (int d = 1; d < 16; d <<= 1) { int t = __shfl_up(ss, d); if (lane >= d) ss += t; }
        if (lane < 16) wtot[lane] = ss - wv;
    }
    __syncthreads();
    if (tid < nb) base[tid] = s - v + wtot[w];
    if (tid == nb - 1) base[nb] = s + wtot[w];   // grand total
}

// ---- P3: place packed (key, weight) into compact coarse-bucket segments ----
// key = (o & 255) << 18 | n   (n < 2^18); weight read SEQUENTIALLY from ws[idx]
__global__ void p3_scatter(const int* __restrict__ os, const float* __restrict__ ws,
                           const int* __restrict__ cnt, const int* __restrict__ base,
                           int2* __restrict__ ent, int total, int nblk, int nb, int d1) {
    __shared__ int cursor[NBMAX];
    int tid = threadIdx.x, blk = blockIdx.x;
    for (int b = tid; b < nb; b += 256)
        cursor[b] = base[b] + cnt[b * nblk + blk];
    __syncthreads();
    int start = blk * ELPB;
    for (int i = 0; i < ELPB / 256; ++i) {
        int idx = start + i * 256 + tid;
        if (idx < total) {
            int o = os[idx];
            int n = idx / d1;            // magic-mul
            float wv = ws[idx];          // sequential, coalesced
            int key = ((o & (BPB - 1)) << 18) | n;
            int d = atomicAdd(&cursor[o >> 8], 1);
            ent[d] = make_int2(key, __float_as_int(wv));
        }
    }
}

// ---- P3b: fine counting-sort within each bucket -> compact ent3 + fbase ----
__global__ void p3b_fine(const int2* __restrict__ ent, const int* __restrict__ base,
                         int2* __restrict__ ent3, int* __restrict__ fbase,
                         int M, int nb) {
    __shared__ int cur[BPB];
    __shared__ int wsum[4];
    int tid = threadIdx.x, lane = tid & 63, w = tid >> 6;
    int bkt = blockIdx.x;
    cur[tid] = 0;
    __syncthreads();
    int s = base[bkt], e = base[bkt + 1];
    for (int p = s + tid; p < e; p += 256)
        atomicAdd(&cur[ent[p].x >> 18], 1);
    __syncthreads();
    int v = cur[tid];
    int sc = v;
    for (int d = 1; d < 64; d <<= 1) { int t = __shfl_up(sc, d); if (lane >= d) sc += t; }
    if (lane == 63) wsum[w] = sc;
    __syncthreads();
    int woff = 0;
    for (int i = 0; i < w; ++i) woff += wsum[i];
    int excl = sc - v + woff;
    fbase[bkt * BPB + tid] = s + excl;
    __syncthreads();
    cur[tid] = excl;                    // reuse as intra-segment cursor
    __syncthreads();
    for (int p = s + tid; p < e; p += 256) {
        int2 kv = ent[p];
        int bl = kv.x >> 18;
        int pos = atomicAdd(&cur[bl], 1);          // LDS-scope
        ent3[s + pos] = make_int2(kv.x & 0x3FFFF, kv.y);
    }
    if (bkt == 0 && tid == 0) fbase[M] = base[nb];
}

// ---- Gather-splat: 16 lanes per lattice row; fp16 inp rows (128 B),
// fp32 accumulate, fp16 store ----
__global__ void gather_splat_kernel(const half4v* __restrict__ inp16,
                                    const int2* __restrict__ ent3,
                                    const int* __restrict__ fbase,
                                    half4v* __restrict__ valsh, int M) {
    int t = blockIdx.x * blockDim.x + threadIdx.x;
    int o = t >> 4;           // lattice row
    int l = t & 15;           // 4-channel slot within row
    if (o >= M) return;
    int lane  = threadIdx.x & 63;
    int gbase = lane & 48;    // first lane of this 16-lane group

    int s = fbase[o];
    int k = fbase[o + 1] - s;
    const int2* bucket = ent3 + s;

    int2 kv  = make_int2(0, 0);
    int2 kvh = make_int2(0, 0);
    if (l < k)      kv  = bucket[l];
    if (l + 16 < k) kvh = bucket[l + 16];

    float4 acc = f4zero();
    int klo = k < 16 ? k : 16;
    for (int i = 0; i < klo; ++i) {
        int   n = __shfl(kv.x, gbase + i);
        float w = __int_as_float(__shfl(kv.y, gbase + i));
        half4v hv = inp16[(size_t)n * 16 + l];
        acc.x += w * (float)hv[0]; acc.y += w * (float)hv[1];
        acc.z += w * (float)hv[2]; acc.w += w * (float)hv[3];
    }
    int khi = k < 32 ? k : 32;
    for (int i = 16; i < khi; ++i) {
        int   n = __shfl(kvh.x, gbase + (i - 16));
        float w = __int_as_float(__shfl(kvh.y, gbase + (i - 16)));
        half4v hv = inp16[(size_t)n * 16 + l];
        acc.x += w * (float)hv[0]; acc.y += w * (float)hv[1];
        acc.z += w * (float)hv[2]; acc.w += w * (float)hv[3];
    }
    for (int i = 32; i < k; ++i) {       // fully general tail, ~never
        int2 kvx = bucket[i];
        float w = __int_as_float(kvx.y);
        half4v hv = inp16[(size_t)kvx.x * 16 + l];
        acc.x += w * (float)hv[0]; acc.y += w * (float)hv[1];
        acc.z += w * (float)hv[2]; acc.w += w * (float)hv[3];
    }
    half4v h;
    h[0] = (_Float16)acc.x; h[1] = (_Float16)acc.y;
    h[2] = (_Float16)acc.z; h[3] = (_Float16)acc.w;
    valsh[(size_t)o * 16 + l] = h;
}

// ---- Blur (fp16 buffers): 8 lanes/row, half8 per lane, fp32 math ----
__global__ void blur_kernel(const half8v* __restrict__ src,
                            const int2* __restrict__ bn,  // [M], 1-based pairs
                            half8v* __restrict__ dst, int M) {
    int t = blockIdx.x * blockDim.x + threadIdx.x;
    int m = t >> 3;
    int l = t & 7;
    if (m >= M) return;
    int2 nn = bn[m];
    half8v a  = src[(size_t)m * 8 + l];
    half8v z  = (half8v)(_Float16)0.f;
    half8v b1 = (nn.x > 0) ? src[(size_t)(nn.x - 1) * 8 + l] : z;
    half8v b2 = (nn.y > 0) ? src[(size_t)(nn.y - 1) * 8 + l] : z;
    half8v r;
#pragma unroll
    for (int i = 0; i < 8; ++i)
        r[i] = (_Float16)((float)a[i] + 0.5f * ((float)b1[i] + (float)b2[i]));
    dst[(size_t)m * 8 + l] = r;
}

// ---- Slice: 8 lanes/point, half8 gathers, fp32 out ----
__global__ void slice_kernel(const half8v* __restrict__ valsh,
                             const float* __restrict__ ws,
                             const int* __restrict__ os,
                             float4* __restrict__ out4, int N, float alpha) {
    int t = blockIdx.x * blockDim.x + threadIdx.x;
    int n = t >> 3;
    int l = t & 7;
    if (n >= N) return;
    float acc[8] = {0.f, 0.f, 0.f, 0.f, 0.f, 0.f, 0.f, 0.f};
#pragma unroll
    for (int j = 0; j < 6; ++j) {
        float w = ws[n * 6 + j];
        int   o = os[n * 6 + j];
        half8v v = valsh[(size_t)o * 8 + l];
#pragma unroll
        for (int i = 0; i < 8; ++i) acc[i] += w * (float)v[i];
    }
    float4 lo = make_float4(acc[0] * alpha, acc[1] * alpha, acc[2] * alpha, acc[3] * alpha);
    float4 hi = make_float4(acc[4] * alpha, acc[5] * alpha, acc[6] * alpha, acc[7] * alpha);
    out4[(size_t)n * 16 + l * 2]     = lo;
    out4[(size_t)n * 16 + l * 2 + 1] = hi;
}

extern "C" void kernel_launch(void* const* d_in, const int* in_sizes, int n_in,
                              void* d_out, int out_size, void* d_ws, size_t ws_size,
                              hipStream_t stream) {
    const float* inp = (const float*)d_in[0];
    const float* ws  = (const float*)d_in[1];
    const int*   os  = (const int*)d_in[2];
    const int*   bn  = (const int*)d_in[3];

    const int N  = in_sizes[0] / CCH;           // 262144
    const int d1 = in_sizes[1] / N;             // 6
    const int M  = in_sizes[3] / (d1 * 2);      // 262144
    const float alpha = 1.0f / (1.0f + exp2f(-(float)(d1 - 1)));

    // fp16 ping-pong vals buffers, both inside d_ws (32 MiB each)
    _Float16* A = (_Float16*)d_ws;
    _Float16* B = A + (size_t)M * CCH;

    const int total = N * d1;                       // 1572864
    const int NB    = (M + BPB - 1) / BPB;          // 1024
    const int NBLK  = (total + ELPB - 1) / ELPB;    // 384

    // Partition scratch + fp16 inp copy inside d_out (~60.5 MB of 64 MiB;
    // all dead before slice writes d_out):
    int*  scratch = (int*)d_out;
    int2* ent   = (int2*)scratch;                   // [total] int2   12.6 MB
    int*  cnt   = scratch + 2 * (size_t)total;      // [NB*NBLK]       1.6 MB
    int*  btot  = cnt + NB * NBLK;                  // [NB]
    int*  base  = btot + NB;                        // [NB+1]
    int*  fbase = base + NB + 1;                    // [M+1]           1.0 MB
    int2* ent3  = (int2*)(fbase + M + 1);           // [total] int2   12.6 MB
    _Float16* inp16 = (_Float16*)(ent3 + total);    // [N*CCH]        32.0 MB

    // --- splat phase (no global atomics, exact compact sort) ---
    const int n4 = N * CCH / 4;
    p1_hist   <<<NBLK, 256, 0, stream>>>(os, cnt, (const float4*)inp,
                                         (half4v*)inp16, n4, total, NBLK, NB);
    p2a_scan  <<<(NB * 64 + 255) / 256, 256, 0, stream>>>(cnt, btot, NBLK, NB);
    p2b_base  <<<1, 1024, 0, stream>>>(btot, base, NB);
    p3_scatter<<<NBLK, 256, 0, stream>>>(os, ws, cnt, base, ent, total, NBLK, NB, d1);
    p3b_fine  <<<NB, 256, 0, stream>>>(ent, base, ent3, fbase, M, NB);

    const int gblocks = (M * 16 + 255) / 256;
    gather_splat_kernel<<<gblocks, 256, 0, stream>>>(
        (const half4v*)inp16, ent3, fbase, (half4v*)A, M);

    // --- blur phase: 6 ping-pong passes (A -> B -> A ... -> A) ---
    const int bblocks = (M * 8 + 255) / 256;
    const _Float16* src = A;
    _Float16* dst = B;
    for (int j = 0; j < d1; ++j) {
        blur_kernel<<<bblocks, 256, 0, stream>>>(
            (const half8v*)src, (const int2*)(bn + (size_t)j * M * 2), (half8v*)dst, M);
        _Float16* tmp = (_Float16*)src; src = dst; dst = tmp;
    }

    // d1=6 passes (even) -> final vals in A; slice reads A, writes d_out
    const int sblocks = (N * 8 + 255) / 256;
    slice_kernel<<<sblocks, 256, 0, stream>>>(
        (const half8v*)src, ws, os, (float4*)d_out, N, alpha);
}

// Round 9
// 284.029 us; speedup vs baseline: 1.0068x; 1.0068x over previous
//
#include <hip/hip_runtime.h>

#define CCH 64     // channels
#define BPB 256    // fine bins per coarse bucket
#define NBMAX 1024 // max coarse buckets (M/BPB = 1024 here)
#define ELPB 4096  // elements per partition block

typedef _Float16 half4v __attribute__((ext_vector_type(4)));   // 8 B
typedef _Float16 half8v __attribute__((ext_vector_type(8)));   // 16 B

__device__ __forceinline__ float4 f4zero() { return make_float4(0.f, 0.f, 0.f, 0.f); }

// ---- P1: per-block histogram of coarse buckets (LDS atomics only).
// Fused: grid-stride fp32->fp16 conversion of inp into inp16 scratch. ----
__global__ void p1_hist(const int* __restrict__ os, int* __restrict__ cnt,
                        const float4* __restrict__ inp4, half4v* __restrict__ inp16,
                        int n4, int total, int nblk, int nb) {
    __shared__ int hist[NBMAX];
    int tid = threadIdx.x;
    for (int b = tid; b < nb; b += 256) hist[b] = 0;
    __syncthreads();
    int start = blockIdx.x * ELPB;
    for (int i = 0; i < ELPB / 256; ++i) {
        int idx = start + i * 256 + tid;
        if (idx < total) atomicAdd(&hist[os[idx] >> 8], 1);
    }
    // fp32 -> fp16 convert of inp (independent, coalesced, grid-stride)
    int gstride = gridDim.x * 256;
    for (int i = blockIdx.x * 256 + tid; i < n4; i += gstride) {
        float4 v = inp4[i];
        half4v h;
        h[0] = (_Float16)v.x; h[1] = (_Float16)v.y;
        h[2] = (_Float16)v.z; h[3] = (_Float16)v.w;
        inp16[i] = h;
    }
    __syncthreads();
    for (int b = tid; b < nb; b += 256)
        cnt[b * nblk + blockIdx.x] = hist[b];
}

// ---- P2a: per-bucket exclusive scan across blocks (one wave per bucket) ----
__global__ void p2a_scan(int* __restrict__ cnt, int* __restrict__ btot,
                         int nblk, int nb) {
    int wid  = (blockIdx.x * blockDim.x + threadIdx.x) >> 6;
    int lane = threadIdx.x & 63;
    if (wid >= nb) return;
    int running = 0;
    for (int c = 0; c < nblk; c += 64) {
        int in_r = (c + lane < nblk);
        int idx = wid * nblk + c + lane;
        int v = in_r ? cnt[idx] : 0;
        int s = v;
        for (int d = 1; d < 64; d <<= 1) { int t = __shfl_up(s, d); if (lane >= d) s += t; }
        if (in_r) cnt[idx] = running + s - v;
        running += __shfl(s, 63);
    }
    if (lane == 0) btot[wid] = running;
}

// ---- P2b: exclusive scan of bucket totals -> base[]; base[nb] = total ----
__global__ void p2b_base(const int* __restrict__ btot, int* __restrict__ base, int nb) {
    __shared__ int wtot[16];
    int tid = threadIdx.x, lane = tid & 63, w = tid >> 6;
    int v = (tid < nb) ? btot[tid] : 0;
    int s = v;
    for (int d = 1; d < 64; d <<= 1) { int t = __shfl_up(s, d); if (lane >= d) s += t; }
    if (lane == 63) wtot[w] = s;
    __syncthreads();
    if (w == 0) {
        int wv = (lane < 16) ? wtot[lane] : 0;
        int ss = wv;
        for (int d = 1; d < 16; d <<= 1) { int t = __shfl_up(ss, d); if (lane >= d) ss += t; }
        if (lane < 16) wtot[lane] = ss - wv;
    }
    __syncthreads();
    if (tid < nb) base[tid] = s - v + wtot[w];
    if (tid == nb - 1) base[nb] = s + wtot[w];   // grand total
}

// ---- P3: place packed (key, weight) into compact coarse-bucket segments ----
// key = (o & 255) << 18 | n   (n < 2^18); weight read SEQUENTIALLY from ws[idx]
__global__ void p3_scatter(const int* __restrict__ os, const float* __restrict__ ws,
                           const int* __restrict__ cnt, const int* __restrict__ base,
                           int2* __restrict__ ent, int total, int nblk, int nb, int d1) {
    __shared__ int cursor[NBMAX];
    int tid = threadIdx.x, blk = blockIdx.x;
    for (int b = tid; b < nb; b += 256)
        cursor[b] = base[b] + cnt[b * nblk + blk];
    __syncthreads();
    int start = blk * ELPB;
    for (int i = 0; i < ELPB / 256; ++i) {
        int idx = start + i * 256 + tid;
        if (idx < total) {
            int o = os[idx];
            int n = idx / d1;            // magic-mul
            float wv = ws[idx];          // sequential, coalesced
            int key = ((o & (BPB - 1)) << 18) | n;
            int d = atomicAdd(&cursor[o >> 8], 1);
            ent[d] = make_int2(key, __float_as_int(wv));
        }
    }
}

// ---- P3b: fine counting-sort within each bucket -> compact ent3 + fbase ----
__global__ void p3b_fine(const int2* __restrict__ ent, const int* __restrict__ base,
                         int2* __restrict__ ent3, int* __restrict__ fbase,
                         int M, int nb) {
    __shared__ int cur[BPB];
    __shared__ int wsum[4];
    int tid = threadIdx.x, lane = tid & 63, w = tid >> 6;
    int bkt = blockIdx.x;
    cur[tid] = 0;
    __syncthreads();
    int s = base[bkt], e = base[bkt + 1];
    for (int p = s + tid; p < e; p += 256)
        atomicAdd(&cur[ent[p].x >> 18], 1);
    __syncthreads();
    int v = cur[tid];
    int sc = v;
    for (int d = 1; d < 64; d <<= 1) { int t = __shfl_up(sc, d); if (lane >= d) sc += t; }
    if (lane == 63) wsum[w] = sc;
    __syncthreads();
    int woff = 0;
    for (int i = 0; i < w; ++i) woff += wsum[i];
    int excl = sc - v + woff;
    fbase[bkt * BPB + tid] = s + excl;
    __syncthreads();
    cur[tid] = excl;                    // reuse as intra-segment cursor
    __syncthreads();
    for (int p = s + tid; p < e; p += 256) {
        int2 kv = ent[p];
        int bl = kv.x >> 18;
        int pos = atomicAdd(&cur[bl], 1);          // LDS-scope
        ent3[s + pos] = make_int2(kv.x & 0x3FFFF, kv.y);
    }
    if (bkt == 0 && tid == 0) fbase[M] = base[nb];
}

// ---- Gather-splat: 16 lanes per lattice row; fp16 inp rows (128 B).
// Two 8-slot static-unrolled predicated batches -> up to 8 loads in
// flight per wave-iteration (MLP), fp32 accumulate, fp16 store. ----
__global__ void gather_splat_kernel(const half4v* __restrict__ inp16,
                                    const int2* __restrict__ ent3,
                                    const int* __restrict__ fbase,
                                    half4v* __restrict__ valsh, int M) {
    int t = blockIdx.x * blockDim.x + threadIdx.x;
    int o = t >> 4;           // lattice row
    int l = t & 15;           // 4-channel slot within row
    if (o >= M) return;
    int lane  = threadIdx.x & 63;
    int gbase = lane & 48;    // first lane of this 16-lane group

    int s = fbase[o];
    int k = fbase[o + 1] - s;
    const int2* bucket = ent3 + s;

    int2 kv  = make_int2(0, 0);
    int2 kvh = make_int2(0, 0);
    if (l < k)      kv  = bucket[l];
    if (l + 16 < k) kvh = bucket[l + 16];

    float4 acc = f4zero();
    int klo = k < 16 ? k : 16;

    // batch 0: entries 0..7 — static indices, predicated, 8 loads in flight
    {
        float wv0, wv1, wv2, wv3, wv4, wv5, wv6, wv7;
        half4v v0, v1, v2, v3, v4, v5, v6, v7;
        wv0=wv1=wv2=wv3=wv4=wv5=wv6=wv7=0.f;
        v0=v1=v2=v3=v4=v5=v6=v7=(half4v)(_Float16)0.f;
#define GS_LOAD(i, W, V) \
        if (i < klo) { \
            int n_ = __shfl(kv.x, gbase + i) & 0x3FFFF; \
            W = __int_as_float(__shfl(kv.y, gbase + i)); \
            V = inp16[(size_t)n_ * 16 + l]; \
        }
        GS_LOAD(0, wv0, v0) GS_LOAD(1, wv1, v1) GS_LOAD(2, wv2, v2) GS_LOAD(3, wv3, v3)
        GS_LOAD(4, wv4, v4) GS_LOAD(5, wv5, v5) GS_LOAD(6, wv6, v6) GS_LOAD(7, wv7, v7)
#undef GS_LOAD
#define GS_FMA(W, V) \
        acc.x += W * (float)V[0]; acc.y += W * (float)V[1]; \
        acc.z += W * (float)V[2]; acc.w += W * (float)V[3];
        GS_FMA(wv0, v0) GS_FMA(wv1, v1) GS_FMA(wv2, v2) GS_FMA(wv3, v3)
        GS_FMA(wv4, v4) GS_FMA(wv5, v5) GS_FMA(wv6, v6) GS_FMA(wv7, v7)
#undef GS_FMA
    }
    // batch 1: entries 8..15 (15% of bins) — same pattern
    if (klo > 8) {
        float wv0, wv1, wv2, wv3, wv4, wv5, wv6, wv7;
        half4v v0, v1, v2, v3, v4, v5, v6, v7;
        wv0=wv1=wv2=wv3=wv4=wv5=wv6=wv7=0.f;
        v0=v1=v2=v3=v4=v5=v6=v7=(half4v)(_Float16)0.f;
#define GS_LOAD(i, W, V) \
        if (8 + i < klo) { \
            int n_ = __shfl(kv.x, gbase + 8 + i) & 0x3FFFF; \
            W = __int_as_float(__shfl(kv.y, gbase + 8 + i)); \
            V = inp16[(size_t)n_ * 16 + l]; \
        }
        GS_LOAD(0, wv0, v0) GS_LOAD(1, wv1, v1) GS_LOAD(2, wv2, v2) GS_LOAD(3, wv3, v3)
        GS_LOAD(4, wv4, v4) GS_LOAD(5, wv5, v5) GS_LOAD(6, wv6, v6) GS_LOAD(7, wv7, v7)
#undef GS_LOAD
#define GS_FMA(W, V) \
        acc.x += W * (float)V[0]; acc.y += W * (float)V[1]; \
        acc.z += W * (float)V[2]; acc.w += W * (float)V[3];
        GS_FMA(wv0, v0) GS_FMA(wv1, v1) GS_FMA(wv2, v2) GS_FMA(wv3, v3)
        GS_FMA(wv4, v4) GS_FMA(wv5, v5) GS_FMA(wv6, v6) GS_FMA(wv7, v7)
#undef GS_FMA
    }
    // entries 16..31 (rare)
    int khi = k < 32 ? k : 32;
    for (int i = 16; i < khi; ++i) {
        int   n = __shfl(kvh.x, gbase + (i - 16)) & 0x3FFFF;
        float w = __int_as_float(__shfl(kvh.y, gbase + (i - 16)));
        half4v hv = inp16[(size_t)n * 16 + l];
        acc.x += w * (float)hv[0]; acc.y += w * (float)hv[1];
        acc.z += w * (float)hv[2]; acc.w += w * (float)hv[3];
    }
    for (int i = 32; i < k; ++i) {       // fully general tail, ~never
        int2 kvx = bucket[i];
        float w = __int_as_float(kvx.y);
        half4v hv = inp16[(size_t)kvx.x * 16 + l];
        acc.x += w * (float)hv[0]; acc.y += w * (float)hv[1];
        acc.z += w * (float)hv[2]; acc.w += w * (float)hv[3];
    }
    half4v h;
    h[0] = (_Float16)acc.x; h[1] = (_Float16)acc.y;
    h[2] = (_Float16)acc.z; h[3] = (_Float16)acc.w;
    valsh[(size_t)o * 16 + l] = h;
}

// ---- Blur (fp16 buffers): 2 rows per thread, 8 lanes/row, half8/lane.
// 6 independent gathers + 1 int4 neighbor load in flight per thread. ----
__global__ void blur_kernel(const half8v* __restrict__ src,
                            const int4* __restrict__ bn2,  // [M/2] two 1-based pairs
                            half8v* __restrict__ dst, int M) {
    int t = blockIdx.x * blockDim.x + threadIdx.x;
    int m2 = t >> 3;           // row-pair index
    int l  = t & 7;
    if (m2 >= (M >> 1)) return;
    int m0 = m2 * 2, m1 = m0 + 1;
    int4 nn = bn2[m2];
    half8v z = (half8v)(_Float16)0.f;
    half8v a0  = src[(size_t)m0 * 8 + l];
    half8v a1  = src[(size_t)m1 * 8 + l];
    half8v b0a = (nn.x > 0) ? src[(size_t)(nn.x - 1) * 8 + l] : z;
    half8v b0b = (nn.y > 0) ? src[(size_t)(nn.y - 1) * 8 + l] : z;
    half8v b1a = (nn.z > 0) ? src[(size_t)(nn.z - 1) * 8 + l] : z;
    half8v b1b = (nn.w > 0) ? src[(size_t)(nn.w - 1) * 8 + l] : z;
    half8v r0, r1;
#pragma unroll
    for (int i = 0; i < 8; ++i) {
        r0[i] = (_Float16)((float)a0[i] + 0.5f * ((float)b0a[i] + (float)b0b[i]));
        r1[i] = (_Float16)((float)a1[i] + 0.5f * ((float)b1a[i] + (float)b1b[i]));
    }
    dst[(size_t)m0 * 8 + l] = r0;
    dst[(size_t)m1 * 8 + l] = r1;
}

// ---- Slice: 8 lanes/point, half8 gathers, fp32 out ----
__global__ void slice_kernel(const half8v* __restrict__ valsh,
                             const float* __restrict__ ws,
                             const int* __restrict__ os,
                             float4* __restrict__ out4, int N, float alpha) {
    int t = blockIdx.x * blockDim.x + threadIdx.x;
    int n = t >> 3;
    int l = t & 7;
    if (n >= N) return;
    float acc[8] = {0.f, 0.f, 0.f, 0.f, 0.f, 0.f, 0.f, 0.f};
#pragma unroll
    for (int j = 0; j < 6; ++j) {
        float w = ws[n * 6 + j];
        int   o = os[n * 6 + j];
        half8v v = valsh[(size_t)o * 8 + l];
#pragma unroll
        for (int i = 0; i < 8; ++i) acc[i] += w * (float)v[i];
    }
    float4 lo = make_float4(acc[0] * alpha, acc[1] * alpha, acc[2] * alpha, acc[3] * alpha);
    float4 hi = make_float4(acc[4] * alpha, acc[5] * alpha, acc[6] * alpha, acc[7] * alpha);
    out4[(size_t)n * 16 + l * 2]     = lo;
    out4[(size_t)n * 16 + l * 2 + 1] = hi;
}

extern "C" void kernel_launch(void* const* d_in, const int* in_sizes, int n_in,
                              void* d_out, int out_size, void* d_ws, size_t ws_size,
                              hipStream_t stream) {
    const float* inp = (const float*)d_in[0];
    const float* ws  = (const float*)d_in[1];
    const int*   os  = (const int*)d_in[2];
    const int*   bn  = (const int*)d_in[3];

    const int N  = in_sizes[0] / CCH;           // 262144
    const int d1 = in_sizes[1] / N;             // 6
    const int M  = in_sizes[3] / (d1 * 2);      // 262144
    const float alpha = 1.0f / (1.0f + exp2f(-(float)(d1 - 1)));

    // fp16 ping-pong vals buffers, both inside d_ws (32 MiB each)
    _Float16* A = (_Float16*)d_ws;
    _Float16* B = A + (size_t)M * CCH;

    const int total = N * d1;                       // 1572864
    const int NB    = (M + BPB - 1) / BPB;          // 1024
    const int NBLK  = (total + ELPB - 1) / ELPB;    // 384

    // Partition scratch + fp16 inp copy inside d_out (~60.5 MB of 64 MiB;
    // all dead before slice writes d_out):
    int*  scratch = (int*)d_out;
    int2* ent   = (int2*)scratch;                   // [total] int2   12.6 MB
    int*  cnt   = scratch + 2 * (size_t)total;      // [NB*NBLK]       1.6 MB
    int*  btot  = cnt + NB * NBLK;                  // [NB]
    int*  base  = btot + NB;                        // [NB+1]
    int*  fbase = base + NB + 1;                    // [M+1]           1.0 MB
    int2* ent3  = (int2*)(fbase + M + 1);           // [total] int2   12.6 MB
    _Float16* inp16 = (_Float16*)(ent3 + total);    // [N*CCH]        32.0 MB

    // --- splat phase (no global atomics, exact compact sort) ---
    const int n4 = N * CCH / 4;
    p1_hist   <<<NBLK, 256, 0, stream>>>(os, cnt, (const float4*)inp,
                                         (half4v*)inp16, n4, total, NBLK, NB);
    p2a_scan  <<<(NB * 64 + 255) / 256, 256, 0, stream>>>(cnt, btot, NBLK, NB);
    p2b_base  <<<1, 1024, 0, stream>>>(btot, base, NB);
    p3_scatter<<<NBLK, 256, 0, stream>>>(os, ws, cnt, base, ent, total, NBLK, NB, d1);
    p3b_fine  <<<NB, 256, 0, stream>>>(ent, base, ent3, fbase, M, NB);

    const int gblocks = (M * 16 + 255) / 256;
    gather_splat_kernel<<<gblocks, 256, 0, stream>>>(
        (const half4v*)inp16, ent3, fbase, (half4v*)A, M);

    // --- blur phase: 6 ping-pong passes (A -> B -> A ... -> A) ---
    const int bblocks = ((M / 2) * 8 + 255) / 256;
    const _Float16* src = A;
    _Float16* dst = B;
    for (int j = 0; j < d1; ++j) {
        blur_kernel<<<bblocks, 256, 0, stream>>>(
            (const half8v*)src, (const int4*)(bn + (size_t)j * M * 2), (half8v*)dst, M);
        _Float16* tmp = (_Float16*)src; src = dst; dst = tmp;
    }

    // d1=6 passes (even) -> final vals in A; slice reads A, writes d_out
    const int sblocks = (N * 8 + 255) / 256;
    slice_kernel<<<sblocks, 256, 0, stream>>>(
        (const half8v*)src, ws, os, (float4*)d_out, N, alpha);
}

// Round 10
// 271.548 us; speedup vs baseline: 1.0531x; 1.0460x over previous
//
#include <hip/hip_runtime.h>

#define CCH 64     // channels
#define BPB 256    // fine bins per coarse bucket
#define NBMAX 1024 // max coarse buckets (M/BPB = 1024 here)
#define ELPB 4096  // elements per partition block

typedef _Float16 half4v __attribute__((ext_vector_type(4)));   // 8 B
typedef _Float16 half8v __attribute__((ext_vector_type(8)));   // 16 B

__device__ __forceinline__ float4 f4zero() { return make_float4(0.f, 0.f, 0.f, 0.f); }

// ---- P1: per-block histogram of coarse buckets (LDS atomics only) ----
__global__ void p1_hist(const int* __restrict__ os, int* __restrict__ cnt,
                        int total, int nblk, int nb) {
    __shared__ int hist[NBMAX];
    int tid = threadIdx.x;
    for (int b = tid; b < nb; b += 256) hist[b] = 0;
    __syncthreads();
    int start = blockIdx.x * ELPB;
    for (int i = 0; i < ELPB / 256; ++i) {
        int idx = start + i * 256 + tid;
        if (idx < total) atomicAdd(&hist[os[idx] >> 8], 1);
    }
    __syncthreads();
    for (int b = tid; b < nb; b += 256)
        cnt[b * nblk + blockIdx.x] = hist[b];
}

// ---- P2a: per-bucket exclusive scan across blocks (one wave per bucket) ----
__global__ void p2a_scan(int* __restrict__ cnt, int* __restrict__ btot,
                         int nblk, int nb) {
    int wid  = (blockIdx.x * blockDim.x + threadIdx.x) >> 6;
    int lane = threadIdx.x & 63;
    if (wid >= nb) return;
    int running = 0;
    for (int c = 0; c < nblk; c += 64) {
        int in_r = (c + lane < nblk);
        int idx = wid * nblk + c + lane;
        int v = in_r ? cnt[idx] : 0;
        int s = v;
        for (int d = 1; d < 64; d <<= 1) { int t = __shfl_up(s, d); if (lane >= d) s += t; }
        if (in_r) cnt[idx] = running + s - v;
        running += __shfl(s, 63);
    }
    if (lane == 0) btot[wid] = running;
}

// ---- P2b: exclusive scan of bucket totals -> base[]; base[nb] = total ----
__global__ void p2b_base(const int* __restrict__ btot, int* __restrict__ base, int nb) {
    __shared__ int wtot[16];
    int tid = threadIdx.x, lane = tid & 63, w = tid >> 6;
    int v = (tid < nb) ? btot[tid] : 0;
    int s = v;
    for (int d = 1; d < 64; d <<= 1) { int t = __shfl_up(s, d); if (lane >= d) s += t; }
    if (lane == 63) wtot[w] = s;
    __syncthreads();
    if (w == 0) {
        int wv = (lane < 16) ? wtot[lane] : 0;
        int ss = wv;
        for (int d = 1; d < 16; d <<= 1) { int t = __shfl_up(ss, d); if (lane >= d) ss += t; }
        if (lane < 16) wtot[lane] = ss - wv;
    }
    __syncthreads();
    if (tid < nb) base[tid] = s - v + wtot[w];
    if (tid == nb - 1) base[nb] = s + wtot[w];   // grand total
}

// ---- P3: place packed (key, weight) into compact coarse-bucket segments ----
// key = (o & 255) << 18 | n   (n < 2^18); weight read SEQUENTIALLY from ws[idx]
__global__ void p3_scatter(const int* __restrict__ os, const float* __restrict__ ws,
                           const int* __restrict__ cnt, const int* __restrict__ base,
                           int2* __restrict__ ent, int total, int nblk, int nb, int d1) {
    __shared__ int cursor[NBMAX];
    int tid = threadIdx.x, blk = blockIdx.x;
    for (int b = tid; b < nb; b += 256)
        cursor[b] = base[b] + cnt[b * nblk + blk];
    __syncthreads();
    int start = blk * ELPB;
    for (int i = 0; i < ELPB / 256; ++i) {
        int idx = start + i * 256 + tid;
        if (idx < total) {
            int o = os[idx];
            int n = idx / d1;            // magic-mul
            float wv = ws[idx];          // sequential, coalesced
            int key = ((o & (BPB - 1)) << 18) | n;
            int d = atomicAdd(&cursor[o >> 8], 1);
            ent[d] = make_int2(key, __float_as_int(wv));
        }
    }
}

// ---- P3b: fine counting-sort within each bucket -> compact ent3 + fbase ----
__global__ void p3b_fine(const int2* __restrict__ ent, const int* __restrict__ base,
                         int2* __restrict__ ent3, int* __restrict__ fbase,
                         int M, int nb) {
    __shared__ int cur[BPB];
    __shared__ int wsum[4];
    int tid = threadIdx.x, lane = tid & 63, w = tid >> 6;
    int bkt = blockIdx.x;
    cur[tid] = 0;
    __syncthreads();
    int s = base[bkt], e = base[bkt + 1];
    for (int p = s + tid; p < e; p += 256)
        atomicAdd(&cur[ent[p].x >> 18], 1);
    __syncthreads();
    int v = cur[tid];
    int sc = v;
    for (int d = 1; d < 64; d <<= 1) { int t = __shfl_up(sc, d); if (lane >= d) sc += t; }
    if (lane == 63) wsum[w] = sc;
    __syncthreads();
    int woff = 0;
    for (int i = 0; i < w; ++i) woff += wsum[i];
    int excl = sc - v + woff;
    fbase[bkt * BPB + tid] = s + excl;
    __syncthreads();
    cur[tid] = excl;                    // reuse as intra-segment cursor
    __syncthreads();
    for (int p = s + tid; p < e; p += 256) {
        int2 kv = ent[p];
        int bl = kv.x >> 18;
        int pos = atomicAdd(&cur[bl], 1);          // LDS-scope
        ent3[s + pos] = make_int2(kv.x & 0x3FFFF, kv.y);
    }
    if (bkt == 0 && tid == 0) fbase[M] = base[nb];
}

// ---- Gather-splat: 16 lanes per lattice row; fp32 inp rows (256 B),
// two 8-slot static-unrolled predicated batches, fp32 acc, fp16 store ----
__global__ void gather_splat_kernel(const float4* __restrict__ inp4,
                                    const int2* __restrict__ ent3,
                                    const int* __restrict__ fbase,
                                    half4v* __restrict__ valsh, int M) {
    int t = blockIdx.x * blockDim.x + threadIdx.x;
    int o = t >> 4;           // lattice row
    int l = t & 15;           // 4-channel slot within row
    if (o >= M) return;
    int lane  = threadIdx.x & 63;
    int gbase = lane & 48;    // first lane of this 16-lane group

    int s = fbase[o];
    int k = fbase[o + 1] - s;
    const int2* bucket = ent3 + s;

    int2 kv  = make_int2(0, 0);
    int2 kvh = make_int2(0, 0);
    if (l < k)      kv  = bucket[l];
    if (l + 16 < k) kvh = bucket[l + 16];

    float4 acc = f4zero();
    int klo = k < 16 ? k : 16;

    // batch 0: entries 0..7 — static indices, predicated, 8 loads in flight
    {
        float wv0, wv1, wv2, wv3, wv4, wv5, wv6, wv7;
        float4 v0, v1, v2, v3, v4, v5, v6, v7;
        wv0=wv1=wv2=wv3=wv4=wv5=wv6=wv7=0.f;
        v0=v1=v2=v3=v4=v5=v6=v7=f4zero();
#define GS_LOAD(i, W, V) \
        if (i < klo) { \
            int n_ = __shfl(kv.x, gbase + i) & 0x3FFFF; \
            W = __int_as_float(__shfl(kv.y, gbase + i)); \
            V = inp4[(size_t)n_ * 16 + l]; \
        }
        GS_LOAD(0, wv0, v0) GS_LOAD(1, wv1, v1) GS_LOAD(2, wv2, v2) GS_LOAD(3, wv3, v3)
        GS_LOAD(4, wv4, v4) GS_LOAD(5, wv5, v5) GS_LOAD(6, wv6, v6) GS_LOAD(7, wv7, v7)
#undef GS_LOAD
#define GS_FMA(W, V) \
        acc.x += W * V.x; acc.y += W * V.y; acc.z += W * V.z; acc.w += W * V.w;
        GS_FMA(wv0, v0) GS_FMA(wv1, v1) GS_FMA(wv2, v2) GS_FMA(wv3, v3)
        GS_FMA(wv4, v4) GS_FMA(wv5, v5) GS_FMA(wv6, v6) GS_FMA(wv7, v7)
#undef GS_FMA
    }
    // batch 1: entries 8..15 (~15% of bins)
    if (klo > 8) {
        float wv0, wv1, wv2, wv3, wv4, wv5, wv6, wv7;
        float4 v0, v1, v2, v3, v4, v5, v6, v7;
        wv0=wv1=wv2=wv3=wv4=wv5=wv6=wv7=0.f;
        v0=v1=v2=v3=v4=v5=v6=v7=f4zero();
#define GS_LOAD(i, W, V) \
        if (8 + i < klo) { \
            int n_ = __shfl(kv.x, gbase + 8 + i) & 0x3FFFF; \
            W = __int_as_float(__shfl(kv.y, gbase + 8 + i)); \
            V = inp4[(size_t)n_ * 16 + l]; \
        }
        GS_LOAD(0, wv0, v0) GS_LOAD(1, wv1, v1) GS_LOAD(2, wv2, v2) GS_LOAD(3, wv3, v3)
        GS_LOAD(4, wv4, v4) GS_LOAD(5, wv5, v5) GS_LOAD(6, wv6, v6) GS_LOAD(7, wv7, v7)
#undef GS_LOAD
#define GS_FMA(W, V) \
        acc.x += W * V.x; acc.y += W * V.y; acc.z += W * V.z; acc.w += W * V.w;
        GS_FMA(wv0, v0) GS_FMA(wv1, v1) GS_FMA(wv2, v2) GS_FMA(wv3, v3)
        GS_FMA(wv4, v4) GS_FMA(wv5, v5) GS_FMA(wv6, v6) GS_FMA(wv7, v7)
#undef GS_FMA
    }
    // entries 16..31 (rare)
    int khi = k < 32 ? k : 32;
    for (int i = 16; i < khi; ++i) {
        int   n = __shfl(kvh.x, gbase + (i - 16)) & 0x3FFFF;
        float w = __int_as_float(__shfl(kvh.y, gbase + (i - 16)));
        float4 v = inp4[(size_t)n * 16 + l];
        acc.x += w * v.x; acc.y += w * v.y; acc.z += w * v.z; acc.w += w * v.w;
    }
    for (int i = 32; i < k; ++i) {       // fully general tail, ~never
        int2 kvx = bucket[i];
        float w = __int_as_float(kvx.y);
        float4 v = inp4[(size_t)kvx.x * 16 + l];
        acc.x += w * v.x; acc.y += w * v.y; acc.z += w * v.z; acc.w += w * v.w;
    }
    half4v h;
    h[0] = (_Float16)acc.x; h[1] = (_Float16)acc.y;
    h[2] = (_Float16)acc.z; h[3] = (_Float16)acc.w;
    valsh[(size_t)o * 16 + l] = h;
}

// ---- Blur (fp16 buffers): 2 rows per thread, 8 lanes/row, half8/lane ----
__global__ void blur_kernel(const half8v* __restrict__ src,
                            const int4* __restrict__ bn2,  // [M/2] two 1-based pairs
                            half8v* __restrict__ dst, int M) {
    int t = blockIdx.x * blockDim.x + threadIdx.x;
    int m2 = t >> 3;           // row-pair index
    int l  = t & 7;
    if (m2 >= (M >> 1)) return;
    int m0 = m2 * 2, m1 = m0 + 1;
    int4 nn = bn2[m2];
    half8v z = (half8v)(_Float16)0.f;
    half8v a0  = src[(size_t)m0 * 8 + l];
    half8v a1  = src[(size_t)m1 * 8 + l];
    half8v b0a = (nn.x > 0) ? src[(size_t)(nn.x - 1) * 8 + l] : z;
    half8v b0b = (nn.y > 0) ? src[(size_t)(nn.y - 1) * 8 + l] : z;
    half8v b1a = (nn.z > 0) ? src[(size_t)(nn.z - 1) * 8 + l] : z;
    half8v b1b = (nn.w > 0) ? src[(size_t)(nn.w - 1) * 8 + l] : z;
    half8v r0, r1;
#pragma unroll
    for (int i = 0; i < 8; ++i) {
        r0[i] = (_Float16)((float)a0[i] + 0.5f * ((float)b0a[i] + (float)b0b[i]));
        r1[i] = (_Float16)((float)a1[i] + 0.5f * ((float)b1a[i] + (float)b1b[i]));
    }
    dst[(size_t)m0 * 8 + l] = r0;
    dst[(size_t)m1 * 8 + l] = r1;
}

// ---- Slice: 8 lanes/point, half8 gathers, fp32 out ----
__global__ void slice_kernel(const half8v* __restrict__ valsh,
                             const float* __restrict__ ws,
                             const int* __restrict__ os,
                             float4* __restrict__ out4, int N, float alpha) {
    int t = blockIdx.x * blockDim.x + threadIdx.x;
    int n = t >> 3;
    int l = t & 7;
    if (n >= N) return;
    float acc[8] = {0.f, 0.f, 0.f, 0.f, 0.f, 0.f, 0.f, 0.f};
#pragma unroll
    for (int j = 0; j < 6; ++j) {
        float w = ws[n * 6 + j];
        int   o = os[n * 6 + j];
        half8v v = valsh[(size_t)o * 8 + l];
#pragma unroll
        for (int i = 0; i < 8; ++i) acc[i] += w * (float)v[i];
    }
    float4 lo = make_float4(acc[0] * alpha, acc[1] * alpha, acc[2] * alpha, acc[3] * alpha);
    float4 hi = make_float4(acc[4] * alpha, acc[5] * alpha, acc[6] * alpha, acc[7] * alpha);
    out4[(size_t)n * 16 + l * 2]     = lo;
    out4[(size_t)n * 16 + l * 2 + 1] = hi;
}

extern "C" void kernel_launch(void* const* d_in, const int* in_sizes, int n_in,
                              void* d_out, int out_size, void* d_ws, size_t ws_size,
                              hipStream_t stream) {
    const float* inp = (const float*)d_in[0];
    const float* ws  = (const float*)d_in[1];
    const int*   os  = (const int*)d_in[2];
    const int*   bn  = (const int*)d_in[3];

    const int N  = in_sizes[0] / CCH;           // 262144
    const int d1 = in_sizes[1] / N;             // 6
    const int M  = in_sizes[3] / (d1 * 2);      // 262144
    const float alpha = 1.0f / (1.0f + exp2f(-(float)(d1 - 1)));

    // fp16 ping-pong vals buffers, both inside d_ws (32 MiB each)
    _Float16* A = (_Float16*)d_ws;
    _Float16* B = A + (size_t)M * CCH;

    const int total = N * d1;                       // 1572864
    const int NB    = (M + BPB - 1) / BPB;          // 1024
    const int NBLK  = (total + ELPB - 1) / ELPB;    // 384

    // Partition scratch inside d_out (all dead before slice writes d_out):
    int*  scratch = (int*)d_out;
    int2* ent   = (int2*)scratch;                   // [total] int2   12.6 MB
    int*  cnt   = scratch + 2 * (size_t)total;      // [NB*NBLK]       1.6 MB
    int*  btot  = cnt + NB * NBLK;                  // [NB]
    int*  base  = btot + NB;                        // [NB+1]
    int*  fbase = base + NB + 1;                    // [M+1]           1.0 MB
    int2* ent3  = (int2*)(fbase + M + 1);           // [total] int2   12.6 MB

    // --- splat phase (no global atomics, exact compact sort) ---
    p1_hist   <<<NBLK, 256, 0, stream>>>(os, cnt, total, NBLK, NB);
    p2a_scan  <<<(NB * 64 + 255) / 256, 256, 0, stream>>>(cnt, btot, NBLK, NB);
    p2b_base  <<<1, 1024, 0, stream>>>(btot, base, NB);
    p3_scatter<<<NBLK, 256, 0, stream>>>(os, ws, cnt, base, ent, total, NBLK, NB, d1);
    p3b_fine  <<<NB, 256, 0, stream>>>(ent, base, ent3, fbase, M, NB);

    const int gblocks = (M * 16 + 255) / 256;
    gather_splat_kernel<<<gblocks, 256, 0, stream>>>(
        (const float4*)inp, ent3, fbase, (half4v*)A, M);

    // --- blur phase: 6 ping-pong passes (A -> B -> A ... -> A) ---
    const int bblocks = ((M / 2) * 8 + 255) / 256;
    const _Float16* src = A;
    _Float16* dst = B;
    for (int j = 0; j < d1; ++j) {
        blur_kernel<<<bblocks, 256, 0, stream>>>(
            (const half8v*)src, (const int4*)(bn + (size_t)j * M * 2), (half8v*)dst, M);
        _Float16* tmp = (_Float16*)src; src = dst; dst = tmp;
    }

    // d1=6 passes (even) -> final vals in A; slice reads A, writes d_out
    const int sblocks = (N * 8 + 255) / 256;
    slice_kernel<<<sblocks, 256, 0, stream>>>(
        (const half8v*)src, ws, os, (float4*)d_out, N, alpha);
}